// Round 10
// baseline (415.173 us; speedup 1.0000x reference)
//
#include <hip/hip_runtime.h>
#include <hip/hip_bf16.h>
#include <math.h>

// Shapes (fixed by setup_inputs): B=4, N=16384, V=6, C=384, H=W=32
#define B_ 4
#define N_ 16384
#define V_ 6
#define C_ 384
#define H_ 32
#define W_ 32
#define HW_ 1024
#define BN_ (B_ * N_)

__device__ __forceinline__ float gelu_f(float x){
  return 0.5f * x * (1.0f + erff(x * 0.70710678118654752440f));
}
__device__ __forceinline__ float sigmoid_f(float x){
  return 1.0f / (1.0f + expf(-x));
}
__device__ __forceinline__ float wsum64(float v){
  #pragma unroll
  for (int m = 1; m < 64; m <<= 1) v += __shfl_xor(v, m);
  return v;
}

// ---------------- K0: proj[bv][pix][j] = sum_c vf[bv][c][pix] * w1[c][j] ----
// (unchanged r5 version) grid = 768 blocks; block = 512
__global__ __launch_bounds__(512) void k0_proj(
    const float* __restrict__ vf, const float* __restrict__ w1,
    float* __restrict__ proj)
{
  const int bv  = blockIdx.x >> 5;             // 0..23
  const int px0 = (blockIdx.x & 31) << 5;      // 32-pixel tile
  __shared__ float fs[64][32];                 // 8 KB chunk
  const int t = threadIdx.x;
  const int j = t & 63;
  const int pg = t >> 6;
  const int sc = t >> 3, sq = t & 7;
  float acc0 = 0.f, acc1 = 0.f, acc2 = 0.f, acc3 = 0.f;

  for (int c0 = 0; c0 < C_; c0 += 64){
    const float4 sv = *(const float4*)&vf[((size_t)bv * C_ + c0 + sc) * HW_
                                          + px0 + sq * 4];
    __syncthreads();
    *(float4*)&fs[sc][sq * 4] = sv;
    __syncthreads();
    for (int c = 0; c < 64; ++c){
      const float w = w1[(c0 + c) * 64 + j];
      const float4 hv = *(const float4*)&fs[c][pg * 4];
      acc0 += hv.x * w;
      acc1 += hv.y * w;
      acc2 += hv.z * w;
      acc3 += hv.w * w;
    }
  }
  const size_t ob = ((size_t)bv * HW_ + px0 + pg * 4) * 64 + j;
  proj[ob]           = acc0;
  proj[ob + 64]      = acc1;
  proj[ob + 128]     = acc2;
  proj[ob + 192]     = acc3;
}

// ---------------- K1: fully fused, ONE THREAD PER POINT --------------------
// No LDS, no shuffles. All reductions in-register; w2/cw/biases are
// wave-uniform -> scalar loads. grid = 1024 blocks x 64
__global__ __launch_bounds__(64) void k1_fused(
    const float* __restrict__ xyz, const float* __restrict__ g14d,
    const float* __restrict__ ext, const float* __restrict__ intr,
    const float* __restrict__ offs, const unsigned char* __restrict__ mask,
    const float* __restrict__ gw1, const float* __restrict__ gb1,
    const float* __restrict__ gw2, const float* __restrict__ gb2,
    const float* __restrict__ proj,
    const float* __restrict__ b1, const float* __restrict__ w2,
    const float* __restrict__ b2, const float* __restrict__ lnw,
    const float* __restrict__ lnb, const float* __restrict__ cw,
    const float* __restrict__ ln1w, const float* __restrict__ ln1b,
    float* __restrict__ fused_out, float* __restrict__ act_out)
{
  const int p = blockIdx.x * 64 + threadIdx.x;    // 0..65535
  const int b = p >> 14;
  const int bu = __builtin_amdgcn_readfirstlane(b);  // wave-uniform batch

  // ---- physics gate (same op order as the passing kernels) ----
  const float* g = g14d + (size_t)p * 14;
  float in0 = fminf(fmaxf(g[4],  0.01f), 10.f);
  float in1 = fminf(fmaxf(g[5],  0.01f), 10.f);
  float in2 = fminf(fmaxf(g[6],  0.01f), 10.f);
  float in3 = fminf(fmaxf(g[11], 0.0f),  1.f);
  float gacc = gb2[0];
  #pragma unroll
  for (int hh = 0; hh < 16; ++hh){
    float tv = gb1[hh] + in0 * gw1[hh] + in1 * gw1[16 + hh]
             + in2 * gw1[32 + hh] + in3 * gw1[48 + hh];
    gacc += gelu_f(tv) * gw2[hh];
  }
  const float gate = sigmoid_f(gacc);

  const float px = xyz[p * 3], py = xyz[p * 3 + 1], pz = xyz[p * 3 + 2];
  const float offx = offs[p * 2], offy = offs[p * 2 + 1];
  const float mval = mask[p] ? 1.f : 0.f;

  float sum_f[32];
  #pragma unroll
  for (int d = 0; d < 32; ++d) sum_f[d] = 0.f;
  float summ = 0.f;

  #pragma unroll 1                                // keep view loop rolled (I$)
  for (int v = 0; v < V_; ++v){
    const float* E = ext  + (size_t)(bu * V_ + v) * 12;   // uniform -> s_load
    const float* I = intr + (size_t)(bu * V_ + v) * 9;
    float c0 = E[0]*px + E[1]*py + E[2]*pz + E[3];
    float c1 = E[4]*px + E[5]*py + E[6]*pz + E[7];
    float c2 = E[8]*px + E[9]*py + E[10]*pz + E[11];
    float u0 = I[0]*c0 + I[1]*c1 + I[2]*c2;
    float u1 = I[3]*c0 + I[4]*c1 + I[5]*c2;
    float u2 = I[6]*c0 + I[7]*c1 + I[8]*c2;
    float depth = fmaxf(u2, 1e-6f);
    float gx = 2.0f * (u0 / depth) / (W_ * 14.0f) - 1.0f + offx;
    float gy = 2.0f * (u1 / depth) / (H_ * 14.0f) - 1.0f + offy;
    float fx = ((gx + 1.0f) * W_ - 1.0f) * 0.5f;
    float fy = ((gy + 1.0f) * H_ - 1.0f) * 0.5f;
    fx = fminf(fmaxf(fx, -4.0f), 36.0f);
    fy = fminf(fmaxf(fy, -4.0f), 36.0f);
    float fx0 = floorf(fx), fy0 = floorf(fy);
    float wx = fx - fx0, wy = fy - fy0;
    int x0 = (int)fx0, y0 = (int)fy0;
    float v00 = (float)((x0 >= 0 && x0 < W_) && (y0 >= 0 && y0 < H_));
    float v10 = (float)((x0 + 1 >= 0 && x0 + 1 < W_) && (y0 >= 0 && y0 < H_));
    float v01 = (float)((x0 >= 0 && x0 < W_) && (y0 + 1 >= 0 && y0 + 1 < H_));
    float v11 = (float)((x0 + 1 >= 0 && x0 + 1 < W_) && (y0 + 1 >= 0 && y0 + 1 < H_));
    float vm = (depth > 0.1f && fabsf(gx) <= 1.0f && fabsf(gy) <= 1.0f) ? mval : 0.f;
    summ += vm;
    const int x0c = min(max(x0, 0), W_ - 1), x1c = min(max(x0 + 1, 0), W_ - 1);
    const int y0c = min(max(y0, 0), H_ - 1), y1c = min(max(y0 + 1, 0), H_ - 1);
    const float wv0 = (1.f - wx) * (1.f - wy) * v00;
    const float wv1 = wx * (1.f - wy) * v10;
    const float wv2 = (1.f - wx) * wy * v01;
    const float wv3 = wx * wy * v11;
    const float* pr = proj + (size_t)(bu * V_ + v) * (HW_ * 64);
    const float* t00p = pr + (y0c * W_ + x0c) * 64;
    const float* t10p = pr + (y0c * W_ + x1c) * 64;
    const float* t01p = pr + (y1c * W_ + x0c) * 64;
    const float* t11p = pr + (y1c * W_ + x1c) * 64;

    float y[32];
    #pragma unroll
    for (int d = 0; d < 32; ++d) y[d] = 0.f;
    #pragma unroll
    for (int q = 0; q < 16; ++q){
      const float4 a0 = *(const float4*)(t00p + q * 4);
      const float4 a1 = *(const float4*)(t10p + q * 4);
      const float4 a2 = *(const float4*)(t01p + q * 4);
      const float4 a3 = *(const float4*)(t11p + q * 4);
      float s0 = wv0 * a0.x; s0 += wv1 * a1.x; s0 += wv2 * a2.x; s0 += wv3 * a3.x;
      float s1 = wv0 * a0.y; s1 += wv1 * a1.y; s1 += wv2 * a2.y; s1 += wv3 * a3.y;
      float s2 = wv0 * a0.z; s2 += wv1 * a1.z; s2 += wv2 * a2.z; s2 += wv3 * a3.z;
      float s3 = wv0 * a0.w; s3 += wv1 * a1.w; s3 += wv2 * a2.w; s3 += wv3 * a3.w;
      const float h0 = gelu_f(s0 + b1[q * 4 + 0]);
      const float h1 = gelu_f(s1 + b1[q * 4 + 1]);
      const float h2 = gelu_f(s2 + b1[q * 4 + 2]);
      const float h3 = gelu_f(s3 + b1[q * 4 + 3]);
      #pragma unroll
      for (int d = 0; d < 32; ++d) y[d] += h0 * w2[(q * 4 + 0) * 32 + d];
      #pragma unroll
      for (int d = 0; d < 32; ++d) y[d] += h1 * w2[(q * 4 + 1) * 32 + d];
      #pragma unroll
      for (int d = 0; d < 32; ++d) y[d] += h2 * w2[(q * 4 + 2) * 32 + d];
      #pragma unroll
      for (int d = 0; d < 32; ++d) y[d] += h3 * w2[(q * 4 + 3) * 32 + d];
    }
    // LayerNorm over 32 dims, fully in-register
    float mean = 0.f;
    #pragma unroll
    for (int d = 0; d < 32; ++d){ y[d] += b2[d]; mean += y[d]; }
    mean *= (1.f / 32.f);
    float var = 0.f;
    #pragma unroll
    for (int d = 0; d < 32; ++d){ float dv = y[d] - mean; var += dv * dv; }
    var *= (1.f / 32.f);
    const float rinv = rsqrtf(var + 1e-5f);
    #pragma unroll
    for (int d = 0; d < 32; ++d){
      float v32 = (y[d] - mean) * rinv * lnw[d] + lnb[d];
      sum_f[d] += v32 * gate * vm;
    }
  }

  const float rden = 1.f / (summ + 1e-6f);
  float fu[32];
  #pragma unroll
  for (int d = 0; d < 32; ++d) fu[d] = sum_f[d] * rden;
  #pragma unroll
  for (int q = 0; q < 8; ++q){
    float4 st;
    st.x = fu[q * 4 + 0]; st.y = fu[q * 4 + 1];
    st.z = fu[q * 4 + 2]; st.w = fu[q * 4 + 3];
    *(float4*)&fused_out[(size_t)p * 32 + q * 4] = st;
  }

  // act = softmax(LN(fused @ cw)) * mask, in-register
  float z[64];
  #pragma unroll
  for (int k = 0; k < 64; ++k) z[k] = 0.f;
  #pragma unroll
  for (int d = 0; d < 32; ++d){
    const float fd = fu[d];
    #pragma unroll
    for (int k = 0; k < 64; ++k) z[k] += fd * cw[d * 64 + k];
  }
  float mean = 0.f;
  #pragma unroll
  for (int k = 0; k < 64; ++k) mean += z[k];
  mean *= (1.f / 64.f);
  float var = 0.f;
  #pragma unroll
  for (int k = 0; k < 64; ++k){ float dz = z[k] - mean; var += dz * dz; }
  var *= (1.f / 64.f);
  const float rinv = rsqrtf(var + 1e-5f);
  #pragma unroll
  for (int k = 0; k < 64; ++k) z[k] = (z[k] - mean) * rinv * ln1w[k] + ln1b[k];
  float mx = z[0];
  #pragma unroll
  for (int k = 1; k < 64; ++k) mx = fmaxf(mx, z[k]);
  float ssum = 0.f;
  #pragma unroll
  for (int k = 0; k < 64; ++k){ z[k] = expf(z[k] - mx); ssum += z[k]; }
  const float rs = 1.f / ssum;
  #pragma unroll
  for (int q = 0; q < 16; ++q){
    float4 st;
    st.x = (z[q * 4 + 0] * rs) * mval; st.y = (z[q * 4 + 1] * rs) * mval;
    st.z = (z[q * 4 + 2] * rs) * mval; st.w = (z[q * 4 + 3] * rs) * mval;
    *(float4*)&act_out[(size_t)p * 64 + q * 4] = st;
  }
}

// ---------------- K2: vlad[b,d,k] += sum_n act*fused ; asum[b,k] += act ----
__global__ __launch_bounds__(256) void k2_vlad(
    const float* __restrict__ fused, const float* __restrict__ act,
    float* __restrict__ vlad_acc, float* __restrict__ asum_acc)
{
  __shared__ float act_s[64][64];
  __shared__ float fu_s[64][32];
  const int b = blockIdx.x >> 6, seg = blockIdx.x & 63;
  const int n0 = seg * 256;
  const int t = threadIdx.x, k = t & 63, dg = t >> 6;
  float vacc[8];
  #pragma unroll
  for (int r = 0; r < 8; ++r) vacc[r] = 0.f;
  float asum = 0.f;

  for (int sc = 0; sc < 4; ++sc){
    int nb = n0 + sc * 64;
    #pragma unroll
    for (int i = 0; i < 16; ++i){
      int idx = t + i * 256;
      act_s[idx >> 6][idx & 63] =
        act[((size_t)((b << 14) + nb + (idx >> 6))) * 64 + (idx & 63)];
    }
    #pragma unroll
    for (int i = 0; i < 8; ++i){
      int idx = t + i * 256;
      fu_s[idx >> 5][idx & 31] =
        fused[((size_t)((b << 14) + nb + (idx >> 5))) * 32 + (idx & 31)];
    }
    __syncthreads();
    for (int i = 0; i < 64; ++i){
      float a = act_s[i][k];
      const float* fr = &fu_s[i][dg * 8];
      #pragma unroll
      for (int r = 0; r < 8; ++r) vacc[r] += a * fr[r];
      if (dg == 0) asum += a;
    }
    __syncthreads();
  }
  #pragma unroll
  for (int r = 0; r < 8; ++r)
    atomicAdd(&vlad_acc[b * 2048 + (dg * 8 + r) * 64 + k], vacc[r]);
  if (dg == 0) atomicAdd(&asum_acc[b * 64 + k], asum);
}

// ---------------- K3a: subtract + intra-norm + global-norm factor ---------
__global__ __launch_bounds__(256) void k3a_norm(
    const float* __restrict__ vlad_acc, const float* __restrict__ asum_acc,
    const float* __restrict__ cw2, float* __restrict__ vs1_g,
    float* __restrict__ ginv_g)
{
  const int b = blockIdx.x, t = threadIdx.x;
  __shared__ float vs[2048];
  __shared__ float denom[64];
  __shared__ float redA[4];
  #pragma unroll
  for (int i = 0; i < 8; ++i){
    int idx = t + i * 256;
    vs[idx] = vlad_acc[b * 2048 + idx]
            - asum_acc[b * 64 + (idx & 63)] * cw2[idx];
  }
  __syncthreads();
  if (t < 64){
    float ss = 0.f;
    #pragma unroll
    for (int dd = 0; dd < 32; ++dd){ float x = vs[dd * 64 + t]; ss += x * x; }
    denom[t] = fmaxf(sqrtf(ss), 1e-12f);
  }
  __syncthreads();
  float ls = 0.f;
  #pragma unroll
  for (int i = 0; i < 8; ++i){
    int idx = t + i * 256;
    float x = vs[idx] / denom[idx & 63];
    vs1_g[b * 2048 + idx] = x;
    ls += x * x;
  }
  ls = wsum64(ls);
  if ((t & 63) == 0) redA[t >> 6] = ls;
  __syncthreads();
  if (t == 0){
    float tot = redA[0] + redA[1] + redA[2] + redA[3];
    ginv_g[b] = 1.0f / fmaxf(sqrtf(tot), 1e-12f);
  }
}

// ---------------- K3b: out_acc[b,o] += vs1-slice @ hw-slice ---------------
__global__ __launch_bounds__(256) void k3b_hw(
    const float* __restrict__ vs1_g, const float* __restrict__ hw,
    float* __restrict__ out_acc)
{
  const int b = blockIdx.x >> 3, ks = blockIdx.x & 7;
  const int t = threadIdx.x;
  __shared__ float xs[256];
  xs[t] = vs1_g[b * 2048 + ks * 256 + t];
  __syncthreads();
  float acc = 0.f;
  #pragma unroll 4
  for (int i = 0; i < 256; ++i)
    acc += xs[i] * hw[(size_t)(ks * 256 + i) * 256 + t];
  atomicAdd(&out_acc[b * 256 + t], acc);
}

// ---------------- K3c: gating LN + final output ---------------------------
__global__ __launch_bounds__(256) void k3c_gate(
    const float* __restrict__ out_acc, const float* __restrict__ ginv_g,
    const float* __restrict__ gww, const float* __restrict__ glnw,
    const float* __restrict__ glnb, float* __restrict__ outp)
{
  const int b = blockIdx.x, t = threadIdx.x;
  __shared__ float out_s[256];
  __shared__ float redB[4], redC[4];
  const float ginv = ginv_g[b];
  const float o = out_acc[b * 256 + t] * ginv;
  out_s[t] = o;
  __syncthreads();
  float gp = 0.f;
  #pragma unroll 4
  for (int i = 0; i < 256; ++i) gp += out_s[i] * gww[i * 256 + t];
  float s1 = wsum64(gp);
  if ((t & 63) == 0) redB[t >> 6] = s1;
  __syncthreads();
  float mean = (redB[0] + redB[1] + redB[2] + redB[3]) * (1.f / 256.f);
  float dv = gp - mean;
  float s2 = wsum64(dv * dv);
  if ((t & 63) == 0) redC[t >> 6] = s2;
  __syncthreads();
  float var = (redC[0] + redC[1] + redC[2] + redC[3]) * (1.f / 256.f);
  float gt = sigmoid_f(dv * rsqrtf(var + 1e-5f) * glnw[t] + glnb[t]);
  outp[b * 256 + t] = o * gt;
}

extern "C" void kernel_launch(void* const* d_in, const int* in_sizes, int n_in,
                              void* d_out, int out_size, void* d_ws, size_t ws_size,
                              hipStream_t stream)
{
  (void)in_sizes; (void)n_in; (void)out_size; (void)ws_size;
  const float* xyz   = (const float*)d_in[0];
  const float* g14d  = (const float*)d_in[1];
  const float* vf    = (const float*)d_in[2];
  const float* ext   = (const float*)d_in[3];
  const float* intr  = (const float*)d_in[4];
  const float* offs  = (const float*)d_in[5];
  const unsigned char* mask = (const unsigned char*)d_in[6];
  const float* gw1   = (const float*)d_in[7];
  const float* gb1   = (const float*)d_in[8];
  const float* gw2   = (const float*)d_in[9];
  const float* gb2   = (const float*)d_in[10];
  const float* bnw1  = (const float*)d_in[11];
  const float* bnb1  = (const float*)d_in[12];
  const float* bnw2  = (const float*)d_in[13];
  const float* bnb2  = (const float*)d_in[14];
  const float* bnlnw = (const float*)d_in[15];
  const float* bnlnb = (const float*)d_in[16];
  const float* cw    = (const float*)d_in[17];
  const float* cw2   = (const float*)d_in[18];
  const float* hw    = (const float*)d_in[19];
  const float* ln1w  = (const float*)d_in[20];
  const float* ln1b  = (const float*)d_in[21];
  const float* gww   = (const float*)d_in[22];
  const float* glnw  = (const float*)d_in[23];
  const float* glnb  = (const float*)d_in[24];

  char* ws = (char*)d_ws;
  float* vlad_acc = (float*)(ws);                      // 32 KB   [zeroed]
  float* asum_acc = (float*)(ws + 32768);              // 1 KB    [zeroed]
  float* out_acc  = (float*)(ws + 33792);              // 4 KB    [zeroed]
  float* ginv_g   = (float*)(ws + 37888);              // 256 B
  float* proj     = (float*)(ws + 38912);              // 6.29 MB
  float* fusedb   = (float*)(ws + 6330368);            // 8 MB
  float* actb     = (float*)(ws + 14718976);           // 16 MB
  float* vs1_g    = (float*)(ws + 31496192);           // 32 KB (end ~31.6 MB)

  hipMemsetAsync(d_ws, 0, 37888, stream);              // vlad+asum+out_acc
  k0_proj  <<<dim3(768),  dim3(512), 0, stream>>>(vf, bnw1, proj);
  k1_fused <<<dim3(1024), dim3(64),  0, stream>>>(
      xyz, g14d, ext, intr, offs, mask, gw1, gb1, gw2, gb2, proj,
      bnb1, bnw2, bnb2, bnlnw, bnlnb, cw, ln1w, ln1b, fusedb, actb);
  k2_vlad  <<<dim3(B_ * 64), dim3(256), 0, stream>>>(fusedb, actb, vlad_acc, asum_acc);
  k3a_norm <<<dim3(B_),   dim3(256), 0, stream>>>(vlad_acc, asum_acc, cw2,
                                                  vs1_g, ginv_g);
  k3b_hw   <<<dim3(32),   dim3(256), 0, stream>>>(vs1_g, hw, out_acc);
  k3c_gate <<<dim3(B_),   dim3(256), 0, stream>>>(out_acc, ginv_g, gww,
                                                  glnw, glnb, (float*)d_out);
}

// Round 11
// 383.526 us; speedup vs baseline: 1.0825x; 1.0825x over previous
//
#include <hip/hip_runtime.h>
#include <hip/hip_bf16.h>
#include <math.h>

// Shapes (fixed by setup_inputs): B=4, N=16384, V=6, C=384, H=W=32
#define B_ 4
#define N_ 16384
#define V_ 6
#define C_ 384
#define H_ 32
#define W_ 32
#define HW_ 1024
#define BN_ (B_ * N_)

__device__ __forceinline__ float gelu_f(float x){
  return 0.5f * x * (1.0f + erff(x * 0.70710678118654752440f));
}
__device__ __forceinline__ float sigmoid_f(float x){
  return 1.0f / (1.0f + expf(-x));
}
__device__ __forceinline__ float wsum64(float v){
  #pragma unroll
  for (int m = 1; m < 64; m <<= 1) v += __shfl_xor(v, m);
  return v;
}

// ---------------- K0: proj[bv][pix][j] = sum_c vf[bv][c][pix] * w1[c][j] ----
// (unchanged r5 version) grid = 768 blocks; block = 512
__global__ __launch_bounds__(512) void k0_proj(
    const float* __restrict__ vf, const float* __restrict__ w1,
    float* __restrict__ proj)
{
  const int bv  = blockIdx.x >> 5;             // 0..23
  const int px0 = (blockIdx.x & 31) << 5;      // 32-pixel tile
  __shared__ float fs[64][32];                 // 8 KB chunk
  const int t = threadIdx.x;
  const int j = t & 63;
  const int pg = t >> 6;
  const int sc = t >> 3, sq = t & 7;
  float acc0 = 0.f, acc1 = 0.f, acc2 = 0.f, acc3 = 0.f;

  for (int c0 = 0; c0 < C_; c0 += 64){
    const float4 sv = *(const float4*)&vf[((size_t)bv * C_ + c0 + sc) * HW_
                                          + px0 + sq * 4];
    __syncthreads();
    *(float4*)&fs[sc][sq * 4] = sv;
    __syncthreads();
    for (int c = 0; c < 64; ++c){
      const float w = w1[(c0 + c) * 64 + j];
      const float4 hv = *(const float4*)&fs[c][pg * 4];
      acc0 += hv.x * w;
      acc1 += hv.y * w;
      acc2 += hv.z * w;
      acc3 += hv.w * w;
    }
  }
  const size_t ob = ((size_t)bv * HW_ + px0 + pg * 4) * 64 + j;
  proj[ob]           = acc0;
  proj[ob + 64]      = acc1;
  proj[ob + 128]     = acc2;
  proj[ob + 192]     = acc3;
}

// ---------------- K1v: per (point, view-pair) — 196608 threads -------------
// thread t: p = t & 65535, vp = t >> 16 (views 2vp, 2vp+1).
// Writes contrib[vp][p][32] = v32_0*vm_0 + v32_1*vm_1 and vmsum (exact int).
// grid = 768 blocks x 256 (3072 waves = 3/SIMD)
__global__ __launch_bounds__(256) void k1v_views(
    const float* __restrict__ xyz, const float* __restrict__ ext,
    const float* __restrict__ intr, const float* __restrict__ offs,
    const unsigned char* __restrict__ mask, const float* __restrict__ proj,
    const float* __restrict__ b1, const float* __restrict__ w2,
    const float* __restrict__ b2, const float* __restrict__ lnw,
    const float* __restrict__ lnb,
    float* __restrict__ contrib, float* __restrict__ vmsumb)
{
  const int t = blockIdx.x * 256 + threadIdx.x;
  const int p = t & (BN_ - 1);
  const int vp = __builtin_amdgcn_readfirstlane(t >> 16);   // 0..2, uniform
  const int b = p >> 14;
  const int bu = __builtin_amdgcn_readfirstlane(b);          // uniform

  const float px = xyz[p * 3], py = xyz[p * 3 + 1], pz = xyz[p * 3 + 2];
  const float offx = offs[p * 2], offy = offs[p * 2 + 1];
  const float mval = mask[p] ? 1.f : 0.f;

  float c[32];
  #pragma unroll
  for (int d = 0; d < 32; ++d) c[d] = 0.f;
  float vmsum = 0.f;

  #pragma unroll 1                              // keep view bodies separate (I$)
  for (int j = 0; j < 2; ++j){
    const int v = vp * 2 + j;
    const float* E = ext  + (size_t)(bu * V_ + v) * 12;    // uniform -> s_load
    const float* I = intr + (size_t)(bu * V_ + v) * 9;
    float c0 = E[0]*px + E[1]*py + E[2]*pz + E[3];
    float c1 = E[4]*px + E[5]*py + E[6]*pz + E[7];
    float c2 = E[8]*px + E[9]*py + E[10]*pz + E[11];
    float u0 = I[0]*c0 + I[1]*c1 + I[2]*c2;
    float u1 = I[3]*c0 + I[4]*c1 + I[5]*c2;
    float u2 = I[6]*c0 + I[7]*c1 + I[8]*c2;
    float depth = fmaxf(u2, 1e-6f);
    float gx = 2.0f * (u0 / depth) / (W_ * 14.0f) - 1.0f + offx;
    float gy = 2.0f * (u1 / depth) / (H_ * 14.0f) - 1.0f + offy;
    float fx = ((gx + 1.0f) * W_ - 1.0f) * 0.5f;
    float fy = ((gy + 1.0f) * H_ - 1.0f) * 0.5f;
    fx = fminf(fmaxf(fx, -4.0f), 36.0f);
    fy = fminf(fmaxf(fy, -4.0f), 36.0f);
    float fx0 = floorf(fx), fy0 = floorf(fy);
    float wx = fx - fx0, wy = fy - fy0;
    int x0 = (int)fx0, y0 = (int)fy0;
    float v00 = (float)((x0 >= 0 && x0 < W_) && (y0 >= 0 && y0 < H_));
    float v10 = (float)((x0 + 1 >= 0 && x0 + 1 < W_) && (y0 >= 0 && y0 < H_));
    float v01 = (float)((x0 >= 0 && x0 < W_) && (y0 + 1 >= 0 && y0 + 1 < H_));
    float v11 = (float)((x0 + 1 >= 0 && x0 + 1 < W_) && (y0 + 1 >= 0 && y0 + 1 < H_));
    float vm = (depth > 0.1f && fabsf(gx) <= 1.0f && fabsf(gy) <= 1.0f) ? mval : 0.f;
    vmsum += vm;
    const int x0c = min(max(x0, 0), W_ - 1), x1c = min(max(x0 + 1, 0), W_ - 1);
    const int y0c = min(max(y0, 0), H_ - 1), y1c = min(max(y0 + 1, 0), H_ - 1);
    const float wv0 = (1.f - wx) * (1.f - wy) * v00;
    const float wv1 = wx * (1.f - wy) * v10;
    const float wv2 = (1.f - wx) * wy * v01;
    const float wv3 = wx * wy * v11;
    const float* pr = proj + (size_t)(bu * V_ + v) * (HW_ * 64);
    const float* t00p = pr + (y0c * W_ + x0c) * 64;
    const float* t10p = pr + (y0c * W_ + x1c) * 64;
    const float* t01p = pr + (y1c * W_ + x0c) * 64;
    const float* t11p = pr + (y1c * W_ + x1c) * 64;

    float y[32];
    #pragma unroll
    for (int d = 0; d < 32; ++d) y[d] = 0.f;
    #pragma unroll 4
    for (int q = 0; q < 16; ++q){
      const float4 a0 = *(const float4*)(t00p + q * 4);
      const float4 a1 = *(const float4*)(t10p + q * 4);
      const float4 a2 = *(const float4*)(t01p + q * 4);
      const float4 a3 = *(const float4*)(t11p + q * 4);
      float s0 = wv0 * a0.x; s0 += wv1 * a1.x; s0 += wv2 * a2.x; s0 += wv3 * a3.x;
      float s1 = wv0 * a0.y; s1 += wv1 * a1.y; s1 += wv2 * a2.y; s1 += wv3 * a3.y;
      float s2 = wv0 * a0.z; s2 += wv1 * a1.z; s2 += wv2 * a2.z; s2 += wv3 * a3.z;
      float s3 = wv0 * a0.w; s3 += wv1 * a1.w; s3 += wv2 * a2.w; s3 += wv3 * a3.w;
      const float h0 = gelu_f(s0 + b1[q * 4 + 0]);
      const float h1 = gelu_f(s1 + b1[q * 4 + 1]);
      const float h2 = gelu_f(s2 + b1[q * 4 + 2]);
      const float h3 = gelu_f(s3 + b1[q * 4 + 3]);
      #pragma unroll
      for (int d = 0; d < 32; ++d) y[d] += h0 * w2[(q * 4 + 0) * 32 + d];
      #pragma unroll
      for (int d = 0; d < 32; ++d) y[d] += h1 * w2[(q * 4 + 1) * 32 + d];
      #pragma unroll
      for (int d = 0; d < 32; ++d) y[d] += h2 * w2[(q * 4 + 2) * 32 + d];
      #pragma unroll
      for (int d = 0; d < 32; ++d) y[d] += h3 * w2[(q * 4 + 3) * 32 + d];
    }
    // LayerNorm over 32 dims, in-register (same order as r10's passing kernel)
    float mean = 0.f;
    #pragma unroll
    for (int d = 0; d < 32; ++d){ y[d] += b2[d]; mean += y[d]; }
    mean *= (1.f / 32.f);
    float var = 0.f;
    #pragma unroll
    for (int d = 0; d < 32; ++d){ float dv = y[d] - mean; var += dv * dv; }
    var *= (1.f / 32.f);
    const float rinv = rsqrtf(var + 1e-5f);
    #pragma unroll
    for (int d = 0; d < 32; ++d){
      float v32 = (y[d] - mean) * rinv * lnw[d] + lnb[d];
      c[d] += v32 * vm;                          // gate applied in k1c
    }
  }

  float* crow = contrib + ((size_t)vp * BN_ + p) * 32;
  #pragma unroll
  for (int q = 0; q < 8; ++q){
    float4 st;
    st.x = c[q * 4 + 0]; st.y = c[q * 4 + 1];
    st.z = c[q * 4 + 2]; st.w = c[q * 4 + 3];
    *(float4*)&crow[q * 4] = st;
  }
  vmsumb[(size_t)vp * BN_ + p] = vmsum;
}

// ---------------- K1c: per-point combine + NetVLAD activations -------------
// grid = 256 blocks x 256 (1024 waves) — light tail
__global__ __launch_bounds__(256) void k1c_combine(
    const float* __restrict__ g14d, const unsigned char* __restrict__ mask,
    const float* __restrict__ gw1, const float* __restrict__ gb1,
    const float* __restrict__ gw2, const float* __restrict__ gb2,
    const float* __restrict__ contrib, const float* __restrict__ vmsumb,
    const float* __restrict__ cw, const float* __restrict__ ln1w,
    const float* __restrict__ ln1b,
    float* __restrict__ fused_out, float* __restrict__ act_out)
{
  const int p = blockIdx.x * 256 + threadIdx.x;

  // physics gate (identical op order)
  const float* g = g14d + (size_t)p * 14;
  float in0 = fminf(fmaxf(g[4],  0.01f), 10.f);
  float in1 = fminf(fmaxf(g[5],  0.01f), 10.f);
  float in2 = fminf(fmaxf(g[6],  0.01f), 10.f);
  float in3 = fminf(fmaxf(g[11], 0.0f),  1.f);
  float gacc = gb2[0];
  #pragma unroll
  for (int hh = 0; hh < 16; ++hh){
    float tv = gb1[hh] + in0 * gw1[hh] + in1 * gw1[16 + hh]
             + in2 * gw1[32 + hh] + in3 * gw1[48 + hh];
    gacc += gelu_f(tv) * gw2[hh];
  }
  const float gate = sigmoid_f(gacc);
  const float mval = mask[p] ? 1.f : 0.f;

  const float summ = (vmsumb[p] + vmsumb[BN_ + p]) + vmsumb[2 * BN_ + p];
  const float rden = 1.f / (summ + 1e-6f);

  float fu[32];
  #pragma unroll
  for (int q = 0; q < 8; ++q){
    const float4 c0 = *(const float4*)&contrib[((size_t)0 * BN_ + p) * 32 + q * 4];
    const float4 c1 = *(const float4*)&contrib[((size_t)1 * BN_ + p) * 32 + q * 4];
    const float4 c2 = *(const float4*)&contrib[((size_t)2 * BN_ + p) * 32 + q * 4];
    fu[q * 4 + 0] = (((c0.x + c1.x) + c2.x) * gate) * rden;
    fu[q * 4 + 1] = (((c0.y + c1.y) + c2.y) * gate) * rden;
    fu[q * 4 + 2] = (((c0.z + c1.z) + c2.z) * gate) * rden;
    fu[q * 4 + 3] = (((c0.w + c1.w) + c2.w) * gate) * rden;
  }
  #pragma unroll
  for (int q = 0; q < 8; ++q){
    float4 st;
    st.x = fu[q * 4 + 0]; st.y = fu[q * 4 + 1];
    st.z = fu[q * 4 + 2]; st.w = fu[q * 4 + 3];
    *(float4*)&fused_out[(size_t)p * 32 + q * 4] = st;
  }

  // act = softmax(LN(fused @ cw)) * mask, in-register (identical to r10)
  float z[64];
  #pragma unroll
  for (int k = 0; k < 64; ++k) z[k] = 0.f;
  #pragma unroll
  for (int d = 0; d < 32; ++d){
    const float fd = fu[d];
    #pragma unroll
    for (int k = 0; k < 64; ++k) z[k] += fd * cw[d * 64 + k];
  }
  float mean = 0.f;
  #pragma unroll
  for (int k = 0; k < 64; ++k) mean += z[k];
  mean *= (1.f / 64.f);
  float var = 0.f;
  #pragma unroll
  for (int k = 0; k < 64; ++k){ float dz = z[k] - mean; var += dz * dz; }
  var *= (1.f / 64.f);
  const float rinv = rsqrtf(var + 1e-5f);
  #pragma unroll
  for (int k = 0; k < 64; ++k) z[k] = (z[k] - mean) * rinv * ln1w[k] + ln1b[k];
  float mx = z[0];
  #pragma unroll
  for (int k = 1; k < 64; ++k) mx = fmaxf(mx, z[k]);
  float ssum = 0.f;
  #pragma unroll
  for (int k = 0; k < 64; ++k){ z[k] = expf(z[k] - mx); ssum += z[k]; }
  const float rs = 1.f / ssum;
  #pragma unroll
  for (int q = 0; q < 16; ++q){
    float4 st;
    st.x = (z[q * 4 + 0] * rs) * mval; st.y = (z[q * 4 + 1] * rs) * mval;
    st.z = (z[q * 4 + 2] * rs) * mval; st.w = (z[q * 4 + 3] * rs) * mval;
    *(float4*)&act_out[(size_t)p * 64 + q * 4] = st;
  }
}

// ---------------- K2: vlad[b,d,k] += sum_n act*fused ; asum[b,k] += act ----
__global__ __launch_bounds__(256) void k2_vlad(
    const float* __restrict__ fused, const float* __restrict__ act,
    float* __restrict__ vlad_acc, float* __restrict__ asum_acc)
{
  __shared__ float act_s[64][64];
  __shared__ float fu_s[64][32];
  const int b = blockIdx.x >> 6, seg = blockIdx.x & 63;
  const int n0 = seg * 256;
  const int t = threadIdx.x, k = t & 63, dg = t >> 6;
  float vacc[8];
  #pragma unroll
  for (int r = 0; r < 8; ++r) vacc[r] = 0.f;
  float asum = 0.f;

  for (int sc = 0; sc < 4; ++sc){
    int nb = n0 + sc * 64;
    #pragma unroll
    for (int i = 0; i < 16; ++i){
      int idx = t + i * 256;
      act_s[idx >> 6][idx & 63] =
        act[((size_t)((b << 14) + nb + (idx >> 6))) * 64 + (idx & 63)];
    }
    #pragma unroll
    for (int i = 0; i < 8; ++i){
      int idx = t + i * 256;
      fu_s[idx >> 5][idx & 31] =
        fused[((size_t)((b << 14) + nb + (idx >> 5))) * 32 + (idx & 31)];
    }
    __syncthreads();
    for (int i = 0; i < 64; ++i){
      float a = act_s[i][k];
      const float* fr = &fu_s[i][dg * 8];
      #pragma unroll
      for (int r = 0; r < 8; ++r) vacc[r] += a * fr[r];
      if (dg == 0) asum += a;
    }
    __syncthreads();
  }
  #pragma unroll
  for (int r = 0; r < 8; ++r)
    atomicAdd(&vlad_acc[b * 2048 + (dg * 8 + r) * 64 + k], vacc[r]);
  if (dg == 0) atomicAdd(&asum_acc[b * 64 + k], asum);
}

// ---------------- K3a: subtract + intra-norm + global-norm factor ---------
__global__ __launch_bounds__(256) void k3a_norm(
    const float* __restrict__ vlad_acc, const float* __restrict__ asum_acc,
    const float* __restrict__ cw2, float* __restrict__ vs1_g,
    float* __restrict__ ginv_g)
{
  const int b = blockIdx.x, t = threadIdx.x;
  __shared__ float vs[2048];
  __shared__ float denom[64];
  __shared__ float redA[4];
  #pragma unroll
  for (int i = 0; i < 8; ++i){
    int idx = t + i * 256;
    vs[idx] = vlad_acc[b * 2048 + idx]
            - asum_acc[b * 64 + (idx & 63)] * cw2[idx];
  }
  __syncthreads();
  if (t < 64){
    float ss = 0.f;
    #pragma unroll
    for (int dd = 0; dd < 32; ++dd){ float x = vs[dd * 64 + t]; ss += x * x; }
    denom[t] = fmaxf(sqrtf(ss), 1e-12f);
  }
  __syncthreads();
  float ls = 0.f;
  #pragma unroll
  for (int i = 0; i < 8; ++i){
    int idx = t + i * 256;
    float x = vs[idx] / denom[idx & 63];
    vs1_g[b * 2048 + idx] = x;
    ls += x * x;
  }
  ls = wsum64(ls);
  if ((t & 63) == 0) redA[t >> 6] = ls;
  __syncthreads();
  if (t == 0){
    float tot = redA[0] + redA[1] + redA[2] + redA[3];
    ginv_g[b] = 1.0f / fmaxf(sqrtf(tot), 1e-12f);
  }
}

// ---------------- K3b: out_acc[b,o] += vs1-slice @ hw-slice ---------------
__global__ __launch_bounds__(256) void k3b_hw(
    const float* __restrict__ vs1_g, const float* __restrict__ hw,
    float* __restrict__ out_acc)
{
  const int b = blockIdx.x >> 3, ks = blockIdx.x & 7;
  const int t = threadIdx.x;
  __shared__ float xs[256];
  xs[t] = vs1_g[b * 2048 + ks * 256 + t];
  __syncthreads();
  float acc = 0.f;
  #pragma unroll 4
  for (int i = 0; i < 256; ++i)
    acc += xs[i] * hw[(size_t)(ks * 256 + i) * 256 + t];
  atomicAdd(&out_acc[b * 256 + t], acc);
}

// ---------------- K3c: gating LN + final output ---------------------------
__global__ __launch_bounds__(256) void k3c_gate(
    const float* __restrict__ out_acc, const float* __restrict__ ginv_g,
    const float* __restrict__ gww, const float* __restrict__ glnw,
    const float* __restrict__ glnb, float* __restrict__ outp)
{
  const int b = blockIdx.x, t = threadIdx.x;
  __shared__ float out_s[256];
  __shared__ float redB[4], redC[4];
  const float ginv = ginv_g[b];
  const float o = out_acc[b * 256 + t] * ginv;
  out_s[t] = o;
  __syncthreads();
  float gp = 0.f;
  #pragma unroll 4
  for (int i = 0; i < 256; ++i) gp += out_s[i] * gww[i * 256 + t];
  float s1 = wsum64(gp);
  if ((t & 63) == 0) redB[t >> 6] = s1;
  __syncthreads();
  float mean = (redB[0] + redB[1] + redB[2] + redB[3]) * (1.f / 256.f);
  float dv = gp - mean;
  float s2 = wsum64(dv * dv);
  if ((t & 63) == 0) redC[t >> 6] = s2;
  __syncthreads();
  float var = (redC[0] + redC[1] + redC[2] + redC[3]) * (1.f / 256.f);
  float gt = sigmoid_f(dv * rsqrtf(var + 1e-5f) * glnw[t] + glnb[t]);
  outp[b * 256 + t] = o * gt;
}

extern "C" void kernel_launch(void* const* d_in, const int* in_sizes, int n_in,
                              void* d_out, int out_size, void* d_ws, size_t ws_size,
                              hipStream_t stream)
{
  (void)in_sizes; (void)n_in; (void)out_size; (void)ws_size;
  const float* xyz   = (const float*)d_in[0];
  const float* g14d  = (const float*)d_in[1];
  const float* vf    = (const float*)d_in[2];
  const float* ext   = (const float*)d_in[3];
  const float* intr  = (const float*)d_in[4];
  const float* offs  = (const float*)d_in[5];
  const unsigned char* mask = (const unsigned char*)d_in[6];
  const float* gw1   = (const float*)d_in[7];
  const float* gb1   = (const float*)d_in[8];
  const float* gw2   = (const float*)d_in[9];
  const float* gb2   = (const float*)d_in[10];
  const float* bnw1  = (const float*)d_in[11];
  const float* bnb1  = (const float*)d_in[12];
  const float* bnw2  = (const float*)d_in[13];
  const float* bnb2  = (const float*)d_in[14];
  const float* bnlnw = (const float*)d_in[15];
  const float* bnlnb = (const float*)d_in[16];
  const float* cw    = (const float*)d_in[17];
  const float* cw2   = (const float*)d_in[18];
  const float* hw    = (const float*)d_in[19];
  const float* ln1w  = (const float*)d_in[20];
  const float* ln1b  = (const float*)d_in[21];
  const float* gww   = (const float*)d_in[22];
  const float* glnw  = (const float*)d_in[23];
  const float* glnb  = (const float*)d_in[24];

  char* ws = (char*)d_ws;
  float* vlad_acc = (float*)(ws);                      // 32 KB   [zeroed]
  float* asum_acc = (float*)(ws + 32768);              // 1 KB    [zeroed]
  float* out_acc  = (float*)(ws + 33792);              // 4 KB    [zeroed]
  float* ginv_g   = (float*)(ws + 37888);              // 256 B
  // proj lives only k0->k1v; fusedb (written by k1c) aliases over it.
  float* proj     = (float*)(ws + 38912);              // 6.29 MB (k0/k1v phase)
  float* fusedb   = (float*)(ws + 38912);              // 8 MB    (k1c+ phase)
  float* contrib  = (float*)(ws + 38912 + 8388608);    // 25.17 MB
  float* vmsumb   = (float*)(ws + 38912 + 8388608 + 25165824);   // 768 KB
  float* actb     = (float*)(ws + 38912 + 8388608 + 25165824 + 786432); // 16 MB
  float* vs1_g    = (float*)(ws + 38912 + 8388608 + 25165824 + 786432
                             + 16777216);              // 32 KB (end ~48.9 MB)

  hipMemsetAsync(d_ws, 0, 37888, stream);              // vlad+asum+out_acc
  k0_proj    <<<dim3(768), dim3(512), 0, stream>>>(vf, bnw1, proj);
  k1v_views  <<<dim3(768), dim3(256), 0, stream>>>(
      xyz, ext, intr, offs, mask, proj,
      bnb1, bnw2, bnb2, bnlnw, bnlnb, contrib, vmsumb);
  k1c_combine<<<dim3(256), dim3(256), 0, stream>>>(
      g14d, mask, gw1, gb1, gw2, gb2, contrib, vmsumb,
      cw, ln1w, ln1b, fusedb, actb);
  k2_vlad    <<<dim3(B_ * 64), dim3(256), 0, stream>>>(fusedb, actb, vlad_acc, asum_acc);
  k3a_norm   <<<dim3(B_),  dim3(256), 0, stream>>>(vlad_acc, asum_acc, cw2,
                                                   vs1_g, ginv_g);
  k3b_hw     <<<dim3(32),  dim3(256), 0, stream>>>(vs1_g, hw, out_acc);
  k3c_gate   <<<dim3(B_),  dim3(256), 0, stream>>>(out_acc, ginv_g, gww,
                                                   glnw, glnb, (float*)d_out);
}